// Round 2
// baseline (2303.019 us; speedup 1.0000x reference)
//
#include <hip/hip_runtime.h>
#include <cstdint>

#define TT 2048
#define DD 256
#define HH 8
#define LL 12

typedef __attribute__((ext_vector_type(8))) short s16x8;
typedef __attribute__((ext_vector_type(4))) float f32x4;

__device__ __forceinline__ unsigned short f2bf(float f) {
  union { float f; unsigned u; } v; v.f = f;
  return (unsigned short)((v.u + 0x7FFFu + ((v.u >> 16) & 1u)) >> 16);
}

__device__ __forceinline__ float geluf(float x) {
  return 0.5f * x * (1.0f + erff(x * 0.70710678118654752f));
}

__device__ __forceinline__ void gload16(const void* g, void* l) {
  __builtin_amdgcn_global_load_lds((const __attribute__((address_space(1))) unsigned int*)g,
                                   (__attribute__((address_space(3))) unsigned int*)l, 16, 0, 0);
}

// ---------------- embedding: h = tok[x] + pos ----------------
__global__ __launch_bounds__(256) void k_embed(const int* __restrict__ x,
                                               const float* __restrict__ tok,
                                               const float* __restrict__ pos,
                                               float* __restrict__ h) {
  int i = blockIdx.x * 256 + threadIdx.x;  // vec4 index, total 8192*64
  int row = i >> 6, c = i & 63;
  int t = x[row];
  f32x4 tv = ((const f32x4*)(tok + (size_t)t * DD))[c];
  f32x4 pv = ((const f32x4*)(pos + (size_t)(row & (TT - 1)) * DD))[c];
  ((f32x4*)(h + (size_t)row * DD))[c] = tv + pv;
}

// ---------------- layernorm (f32 in) -> bf16 out ----------------
__global__ __launch_bounds__(256) void k_ln(const float* __restrict__ h,
                                            const float* __restrict__ wgt,
                                            const float* __restrict__ bia,
                                            unsigned short* __restrict__ z) {
  int row = blockIdx.x * 4 + (threadIdx.x >> 6);
  int lane = threadIdx.x & 63;
  f32x4 v = ((const f32x4*)(h + (size_t)row * DD))[lane];
  float s = v[0] + v[1] + v[2] + v[3];
#pragma unroll
  for (int m = 32; m; m >>= 1) s += __shfl_xor(s, m);
  float mean = s * (1.0f / DD);
  f32x4 d = v - mean;
  float s2 = d[0] * d[0] + d[1] * d[1] + d[2] * d[2] + d[3] * d[3];
#pragma unroll
  for (int m = 32; m; m >>= 1) s2 += __shfl_xor(s2, m);
  float inv = rsqrtf(s2 * (1.0f / DD) + 1e-5f);
  f32x4 wv = ((const f32x4*)wgt)[lane];
  f32x4 bv = ((const f32x4*)bia)[lane];
  union { unsigned short us[4]; unsigned long long u64; } ou;
#pragma unroll
  for (int e = 0; e < 4; ++e) ou.us[e] = f2bf(d[e] * inv * wv[e] + bv[e]);
  *(unsigned long long*)(z + (size_t)row * DD + lane * 4) = ou.u64;
}

// ---------------- weight cast+transpose f32 (K,N) -> bf16 (N,K) ----------------
__global__ __launch_bounds__(256) void k_cast_tr4(const float* __restrict__ qw, const float* __restrict__ ow,
                                                  const float* __restrict__ f1, const float* __restrict__ f2,
                                                  unsigned short* __restrict__ dq, unsigned short* __restrict__ dO,
                                                  unsigned short* __restrict__ d1, unsigned short* __restrict__ d2) {
  int t0 = blockIdx.x * 256 + threadIdx.x;
  int stride = gridDim.x * 256;
  for (int i = t0; i < 256 * 768; i += stride) { int k = i / 768, n = i % 768; dq[n * 256 + k] = f2bf(qw[i]); }
  for (int i = t0; i < 256 * 256; i += stride) { int k = i >> 8, n = i & 255; dO[n * 256 + k] = f2bf(ow[i]); }
  for (int i = t0; i < 256 * 1024; i += stride) { int k = i >> 10, n = i & 1023; d1[n * 256 + k] = f2bf(f1[i]); }
  for (int i = t0; i < 1024 * 256; i += stride) { int k = i >> 8, n = i & 255; d2[n * 1024 + k] = f2bf(f2[i]); }
}

__global__ __launch_bounds__(256) void k_cast_tr256(const float* __restrict__ src, unsigned short* __restrict__ dst) {
  int i = blockIdx.x * 256 + threadIdx.x;  // 256x256
  int k = i >> 8, n = i & 255;
  dst[n * 256 + k] = f2bf(src[i]);
}

// ---------------- GEMM: C[M,N] = A[M,K](bf16) * BT[N,K]^T(bf16) + bias ----------------
// MODE 0: bf16 store; 1: gelu->bf16; 2: f32 resid+store; 3: f32 store
template <int MODE, int MI>
__global__ __launch_bounds__(256) void k_gemm(const unsigned short* __restrict__ A,
                                              const unsigned short* __restrict__ BT,
                                              const float* __restrict__ bias,
                                              void* out, const float* resid,
                                              int M, int N, int K) {
  __shared__ __align__(16) unsigned short As[MI * 32 * 64];
  __shared__ __align__(16) unsigned short Bs[128 * 64];
  const int tid = threadIdx.x;
  const int lane = tid & 63, wv = tid >> 6;
  const int wr = wv >> 1, wc = wv & 1;
  const int l15 = lane & 15, g = lane >> 4;
  const int BM = MI * 32;
  const int tm = blockIdx.y, tn = blockIdx.x;
  f32x4 acc[MI][4] = {};
  const int nk = K >> 6;
  const unsigned short* Ag0 = A + (size_t)tm * BM * K;
  const unsigned short* Bg0 = BT + (size_t)tn * 128 * K;
  for (int kt = 0; kt < nk; ++kt) {
#pragma unroll
    for (int it = 0; it < MI; ++it) {
      int chunk = it * 256 + tid;
      int row = chunk >> 3, part = chunk & 7;
      gload16(Ag0 + (size_t)row * K + kt * 64 + part * 8, As + chunk * 8);
    }
#pragma unroll
    for (int it = 0; it < 4; ++it) {
      int chunk = it * 256 + tid;
      int row = chunk >> 3, part = chunk & 7;
      gload16(Bg0 + (size_t)row * K + kt * 64 + part * 8, Bs + chunk * 8);
    }
    __syncthreads();
#pragma unroll
    for (int ks = 0; ks < 2; ++ks) {
      s16x8 af[MI], bf[4];
#pragma unroll
      for (int mi = 0; mi < MI; ++mi)
        af[mi] = *(const s16x8*)(As + (wr * MI * 16 + mi * 16 + l15) * 64 + ks * 32 + g * 8);
#pragma unroll
      for (int ni = 0; ni < 4; ++ni)
        bf[ni] = *(const s16x8*)(Bs + (wc * 64 + ni * 16 + l15) * 64 + ks * 32 + g * 8);
#pragma unroll
      for (int mi = 0; mi < MI; ++mi)
#pragma unroll
        for (int ni = 0; ni < 4; ++ni)
          acc[mi][ni] = __builtin_amdgcn_mfma_f32_16x16x32_bf16(af[mi], bf[ni], acc[mi][ni], 0, 0, 0);
    }
    __syncthreads();
  }
#pragma unroll
  for (int ni = 0; ni < 4; ++ni) {
    int col = tn * 128 + wc * 64 + ni * 16 + l15;
    float bv = bias[col];
#pragma unroll
    for (int mi = 0; mi < MI; ++mi) {
      int row0 = tm * BM + wr * MI * 16 + mi * 16 + g * 4;
#pragma unroll
      for (int r = 0; r < 4; ++r) {
        size_t idx = (size_t)(row0 + r) * N + col;
        float vvv = acc[mi][ni][r] + bv;
        if (MODE == 0) ((unsigned short*)out)[idx] = f2bf(vvv);
        else if (MODE == 1) ((unsigned short*)out)[idx] = f2bf(geluf(vvv));
        else if (MODE == 2) ((float*)out)[idx] = resid[idx] + vvv;
        else ((float*)out)[idx] = vvv;
      }
    }
  }
}

// ---------------- fused causal flash attention ----------------
// qkv: (B,T,768) bf16 rows = [q(8x32) k(8x32) v(8x32)]; o: (B,T,256) bf16
__global__ __launch_bounds__(256) void k_attn(const unsigned short* __restrict__ qkv,
                                              unsigned short* __restrict__ o) {
  __shared__ __align__(16) unsigned short Ks[64 * 40];
  __shared__ __align__(16) unsigned short Vs[32 * 72];
  __shared__ __align__(16) unsigned short Ps[4 * 16 * 72];
  const int tid = threadIdx.x, lane = tid & 63, w = tid >> 6;
  const int l15 = lane & 15, g = lane >> 4;
  const int qt = blockIdx.x;
  const int b = blockIdx.y >> 3, hh = blockIdx.y & 7;
  const size_t base = (size_t)b * TT * 768;
  const int qrow = qt * 64 + w * 16 + l15;
  s16x8 aq = *(const s16x8*)(qkv + base + (size_t)qrow * 768 + hh * 32 + g * 8);
  f32x4 accO[2] = {};
  float m[4] = {-__builtin_inff(), -__builtin_inff(), -__builtin_inff(), -__builtin_inff()};
  float ls[4] = {0.f, 0.f, 0.f, 0.f};
  const int srow = tid >> 2, spart = tid & 3;
  const float scl = 0.17677669529663687f;  // 1/sqrt(32)
  for (int j = 0; j <= qt; ++j) {
    const size_t krow = base + (size_t)(j * 64 + srow) * 768 + hh * 32 + spart * 8;
    s16x8 kk = *(const s16x8*)(qkv + krow + 256);
    s16x8 vv = *(const s16x8*)(qkv + krow + 512);
    *(s16x8*)(Ks + srow * 40 + spart * 8) = kk;
#pragma unroll
    for (int e = 0; e < 8; ++e) Vs[(spart * 8 + e) * 72 + srow] = (unsigned short)vv[e];
    __syncthreads();
    f32x4 s4[4];
#pragma unroll
    for (int cb = 0; cb < 4; ++cb) {
      s16x8 bk = *(const s16x8*)(Ks + (cb * 16 + l15) * 40 + g * 8);
      f32x4 zz = {};
      s4[cb] = __builtin_amdgcn_mfma_f32_16x16x32_bf16(aq, bk, zz, 0, 0, 0);
    }
#pragma unroll
    for (int cb = 0; cb < 4; ++cb)
#pragma unroll
      for (int r = 0; r < 4; ++r) {
        float sv = s4[cb][r] * scl;
        if (j == qt && (cb * 16 + l15) > (w * 16 + g * 4 + r)) sv = -__builtin_inff();
        s4[cb][r] = sv;
      }
    float rmax[4], rsum[4], al[4];
#pragma unroll
    for (int r = 0; r < 4; ++r)
      rmax[r] = fmaxf(fmaxf(s4[0][r], s4[1][r]), fmaxf(s4[2][r], s4[3][r]));
#pragma unroll
    for (int mk = 1; mk < 16; mk <<= 1)
#pragma unroll
      for (int r = 0; r < 4; ++r) rmax[r] = fmaxf(rmax[r], __shfl_xor(rmax[r], mk));
#pragma unroll
    for (int r = 0; r < 4; ++r) {
      float nm = fmaxf(m[r], rmax[r]);
      al[r] = __expf(m[r] - nm);
      m[r] = nm;
      rsum[r] = 0.f;
    }
#pragma unroll
    for (int cb = 0; cb < 4; ++cb)
#pragma unroll
      for (int r = 0; r < 4; ++r) {
        float p = __expf(s4[cb][r] - m[r]);
        s4[cb][r] = p;
        rsum[r] += p;
      }
#pragma unroll
    for (int mk = 1; mk < 16; mk <<= 1)
#pragma unroll
      for (int r = 0; r < 4; ++r) rsum[r] += __shfl_xor(rsum[r], mk);
#pragma unroll
    for (int r = 0; r < 4; ++r) ls[r] = ls[r] * al[r] + rsum[r];
#pragma unroll
    for (int hb = 0; hb < 2; ++hb)
#pragma unroll
      for (int r = 0; r < 4; ++r) accO[hb][r] *= al[r];
#pragma unroll
    for (int cb = 0; cb < 4; ++cb)
#pragma unroll
      for (int r = 0; r < 4; ++r)
        Ps[w * 1152 + (g * 4 + r) * 72 + cb * 16 + l15] = f2bf(s4[cb][r]);
    __syncthreads();
#pragma unroll
    for (int ks = 0; ks < 2; ++ks) {
      s16x8 pa = *(const s16x8*)(Ps + w * 1152 + l15 * 72 + ks * 32 + g * 8);
#pragma unroll
      for (int hb = 0; hb < 2; ++hb) {
        s16x8 bvv = *(const s16x8*)(Vs + (hb * 16 + l15) * 72 + ks * 32 + g * 8);
        accO[hb] = __builtin_amdgcn_mfma_f32_16x16x32_bf16(pa, bvv, accO[hb], 0, 0, 0);
      }
    }
    __syncthreads();
  }
#pragma unroll
  for (int r = 0; r < 4; ++r) ls[r] = 1.0f / ls[r];
#pragma unroll
  for (int hb = 0; hb < 2; ++hb)
#pragma unroll
    for (int r = 0; r < 4; ++r) {
      int row = qt * 64 + w * 16 + g * 4 + r;
      o[(size_t)(b * TT + row) * DD + hh * 32 + hb * 16 + l15] = f2bf(accO[hb][r] * ls[r]);
    }
}

extern "C" void kernel_launch(void* const* d_in, const int* in_sizes, int n_in,
                              void* d_out, int out_size, void* d_ws, size_t ws_size,
                              hipStream_t stream) {
  const int* x = (const int*)d_in[0];
  const float* tok = (const float*)d_in[1];
  const float* pos = (const float*)d_in[2];
  const float* ln1w = (const float*)d_in[3];
  const float* ln1b = (const float*)d_in[4];
  const float* qkvw = (const float*)d_in[5];
  const float* qkvb = (const float*)d_in[6];
  const float* outw = (const float*)d_in[7];
  const float* outb = (const float*)d_in[8];
  const float* ln2w = (const float*)d_in[9];
  const float* ln2b = (const float*)d_in[10];
  const float* f1w = (const float*)d_in[11];
  const float* f1b = (const float*)d_in[12];
  const float* f2w = (const float*)d_in[13];
  const float* f2b = (const float*)d_in[14];
  const float* lnfw = (const float*)d_in[15];
  const float* lnfb = (const float*)d_in[16];
  const float* hw = (const float*)d_in[17];
  const float* hb = (const float*)d_in[18];

  char* ws = (char*)d_ws;
  float* h = (float*)(ws + 0);                                  //  8 MB
  unsigned short* z = (unsigned short*)(ws + 8388608);          //  4 MB
  unsigned short* qkvB = (unsigned short*)(ws + 12582912);      // 12 MB
  unsigned short* ob = (unsigned short*)(ws + 25165824);        //  4 MB
  unsigned short* a1 = (unsigned short*)(ws + 29360128);        // 16 MB
  unsigned short* wq = (unsigned short*)(ws + 46137344);
  unsigned short* wo = (unsigned short*)(ws + 46530560);
  unsigned short* w1 = (unsigned short*)(ws + 46661632);
  unsigned short* w2 = (unsigned short*)(ws + 47185920);
  unsigned short* wh = (unsigned short*)(ws + 47710208);        // end ~47.9 MB

  k_cast_tr256<<<dim3(256), dim3(256), 0, stream>>>(hw, wh);
  k_embed<<<dim3(2048), dim3(256), 0, stream>>>(x, tok, pos, h);

  for (int l = 0; l < LL; ++l) {
    k_cast_tr4<<<dim3(1024), dim3(256), 0, stream>>>(
        qkvw + (size_t)l * 256 * 768, outw + (size_t)l * 256 * 256,
        f1w + (size_t)l * 256 * 1024, f2w + (size_t)l * 1024 * 256, wq, wo, w1, w2);
    k_ln<<<dim3(2048), dim3(256), 0, stream>>>(h, ln1w + l * 256, ln1b + l * 256, z);
    k_gemm<0, 4><<<dim3(6, 64), dim3(256), 0, stream>>>(z, wq, qkvb + l * 768, qkvB, nullptr, 8192, 768, 256);
    k_attn<<<dim3(32, 32), dim3(256), 0, stream>>>(qkvB, ob);
    k_gemm<2, 2><<<dim3(2, 128), dim3(256), 0, stream>>>(ob, wo, outb + l * 256, h, h, 8192, 256, 256);
    k_ln<<<dim3(2048), dim3(256), 0, stream>>>(h, ln2w + l * 256, ln2b + l * 256, z);
    k_gemm<1, 4><<<dim3(8, 64), dim3(256), 0, stream>>>(z, w1, f1b + l * 1024, a1, nullptr, 8192, 1024, 256);
    k_gemm<2, 2><<<dim3(2, 128), dim3(256), 0, stream>>>(a1, w2, f2b + l * 256, h, h, 8192, 256, 1024);
  }

  k_ln<<<dim3(2048), dim3(256), 0, stream>>>(h, lnfw, lnfb, z);
  k_gemm<3, 2><<<dim3(2, 128), dim3(256), 0, stream>>>(z, wh, hb, d_out, nullptr, 8192, 256, 256);
}

// Round 3
// 1913.292 us; speedup vs baseline: 1.2037x; 1.2037x over previous
//
#include <hip/hip_runtime.h>
#include <cstdint>

#define TT 2048
#define DD 256
#define HH 8
#define LL 12

typedef __attribute__((ext_vector_type(8))) short s16x8;
typedef __attribute__((ext_vector_type(4))) float f32x4;

__device__ __forceinline__ unsigned short f2bf(float f) {
  union { float f; unsigned u; } v; v.f = f;
  return (unsigned short)((v.u + 0x7FFFu + ((v.u >> 16) & 1u)) >> 16);
}

__device__ __forceinline__ float geluf(float x) {
  return 0.5f * x * (1.0f + erff(x * 0.70710678118654752f));
}

__device__ __forceinline__ void gload16(const void* g, void* l) {
  __builtin_amdgcn_global_load_lds((const __attribute__((address_space(1))) unsigned int*)g,
                                   (__attribute__((address_space(3))) unsigned int*)l, 16, 0, 0);
}

// ---------------- embedding: h = tok[x] + pos ----------------
__global__ __launch_bounds__(256) void k_embed(const int* __restrict__ x,
                                               const float* __restrict__ tok,
                                               const float* __restrict__ pos,
                                               float* __restrict__ h) {
  int i = blockIdx.x * 256 + threadIdx.x;  // vec4 index, total 8192*64
  int row = i >> 6, c = i & 63;
  int t = x[row];
  f32x4 tv = ((const f32x4*)(tok + (size_t)t * DD))[c];
  f32x4 pv = ((const f32x4*)(pos + (size_t)(row & (TT - 1)) * DD))[c];
  ((f32x4*)(h + (size_t)row * DD))[c] = tv + pv;
}

// ---------------- layernorm (f32 in) -> bf16 out ----------------
__global__ __launch_bounds__(256) void k_ln(const float* __restrict__ h,
                                            const float* __restrict__ wgt,
                                            const float* __restrict__ bia,
                                            unsigned short* __restrict__ z) {
  int row = blockIdx.x * 4 + (threadIdx.x >> 6);
  int lane = threadIdx.x & 63;
  f32x4 v = ((const f32x4*)(h + (size_t)row * DD))[lane];
  float s = v[0] + v[1] + v[2] + v[3];
#pragma unroll
  for (int m = 32; m; m >>= 1) s += __shfl_xor(s, m);
  float mean = s * (1.0f / DD);
  f32x4 d = v - mean;
  float s2 = d[0] * d[0] + d[1] * d[1] + d[2] * d[2] + d[3] * d[3];
#pragma unroll
  for (int m = 32; m; m >>= 1) s2 += __shfl_xor(s2, m);
  float inv = rsqrtf(s2 * (1.0f / DD) + 1e-5f);
  f32x4 wv = ((const f32x4*)wgt)[lane];
  f32x4 bv = ((const f32x4*)bia)[lane];
  union { unsigned short us[4]; unsigned long long u64; } ou;
#pragma unroll
  for (int e = 0; e < 4; ++e) ou.us[e] = f2bf(d[e] * inv * wv[e] + bv[e]);
  *(unsigned long long*)(z + (size_t)row * DD + lane * 4) = ou.u64;
}

// ---------------- weight cast+transpose f32 (K,N) -> bf16 (N,K) ----------------
__global__ __launch_bounds__(256) void k_cast_tr4(const float* __restrict__ qw, const float* __restrict__ ow,
                                                  const float* __restrict__ f1, const float* __restrict__ f2,
                                                  unsigned short* __restrict__ dq, unsigned short* __restrict__ dO,
                                                  unsigned short* __restrict__ d1, unsigned short* __restrict__ d2) {
  int t0 = blockIdx.x * 256 + threadIdx.x;
  int stride = gridDim.x * 256;
  for (int i = t0; i < 256 * 768; i += stride) { int k = i / 768, n = i % 768; dq[n * 256 + k] = f2bf(qw[i]); }
  for (int i = t0; i < 256 * 256; i += stride) { int k = i >> 8, n = i & 255; dO[n * 256 + k] = f2bf(ow[i]); }
  for (int i = t0; i < 256 * 1024; i += stride) { int k = i >> 10, n = i & 1023; d1[n * 256 + k] = f2bf(f1[i]); }
  for (int i = t0; i < 1024 * 256; i += stride) { int k = i >> 8, n = i & 255; d2[n * 1024 + k] = f2bf(f2[i]); }
}

__global__ __launch_bounds__(256) void k_cast_tr256(const float* __restrict__ src, unsigned short* __restrict__ dst) {
  int i = blockIdx.x * 256 + threadIdx.x;  // 256x256
  int k = i >> 8, n = i & 255;
  dst[n * 256 + k] = f2bf(src[i]);
}

// ---------------- GEMM: C[M,N] = A[M,K](bf16) * BT[N,K]^T(bf16) + bias ----------------
// MODE 0: bf16 store; 1: gelu->bf16; 2: f32 resid+store; 3: f32 store
template <int MODE, int MI>
__global__ __launch_bounds__(256) void k_gemm(const unsigned short* __restrict__ A,
                                              const unsigned short* __restrict__ BT,
                                              const float* __restrict__ bias,
                                              void* out, const float* resid,
                                              int M, int N, int K) {
  __shared__ __align__(16) unsigned short As[MI * 32 * 64];
  __shared__ __align__(16) unsigned short Bs[128 * 64];
  const int tid = threadIdx.x;
  const int lane = tid & 63, wv = tid >> 6;
  const int wr = wv >> 1, wc = wv & 1;
  const int l15 = lane & 15, g = lane >> 4;
  const int BM = MI * 32;
  const int tm = blockIdx.y, tn = blockIdx.x;
  f32x4 acc[MI][4] = {};
  const int nk = K >> 6;
  const unsigned short* Ag0 = A + (size_t)tm * BM * K;
  const unsigned short* Bg0 = BT + (size_t)tn * 128 * K;
  for (int kt = 0; kt < nk; ++kt) {
#pragma unroll
    for (int it = 0; it < MI; ++it) {
      int chunk = it * 256 + tid;
      int row = chunk >> 3, part = chunk & 7;
      gload16(Ag0 + (size_t)row * K + kt * 64 + part * 8, As + chunk * 8);
    }
#pragma unroll
    for (int it = 0; it < 4; ++it) {
      int chunk = it * 256 + tid;
      int row = chunk >> 3, part = chunk & 7;
      gload16(Bg0 + (size_t)row * K + kt * 64 + part * 8, Bs + chunk * 8);
    }
    __syncthreads();
#pragma unroll
    for (int ks = 0; ks < 2; ++ks) {
      s16x8 af[MI], bf[4];
#pragma unroll
      for (int mi = 0; mi < MI; ++mi)
        af[mi] = *(const s16x8*)(As + (wr * MI * 16 + mi * 16 + l15) * 64 + ks * 32 + g * 8);
#pragma unroll
      for (int ni = 0; ni < 4; ++ni)
        bf[ni] = *(const s16x8*)(Bs + (wc * 64 + ni * 16 + l15) * 64 + ks * 32 + g * 8);
#pragma unroll
      for (int mi = 0; mi < MI; ++mi)
#pragma unroll
        for (int ni = 0; ni < 4; ++ni)
          acc[mi][ni] = __builtin_amdgcn_mfma_f32_16x16x32_bf16(af[mi], bf[ni], acc[mi][ni], 0, 0, 0);
    }
    __syncthreads();
  }
#pragma unroll
  for (int ni = 0; ni < 4; ++ni) {
    int col = tn * 128 + wc * 64 + ni * 16 + l15;
    float bv = bias[col];
#pragma unroll
    for (int mi = 0; mi < MI; ++mi) {
      int row0 = tm * BM + wr * MI * 16 + mi * 16 + g * 4;
#pragma unroll
      for (int r = 0; r < 4; ++r) {
        size_t idx = (size_t)(row0 + r) * N + col;
        float vvv = acc[mi][ni][r] + bv;
        if (MODE == 0) ((unsigned short*)out)[idx] = f2bf(vvv);
        else if (MODE == 1) ((unsigned short*)out)[idx] = f2bf(geluf(vvv));
        else if (MODE == 2) ((float*)out)[idx] = resid[idx] + vvv;
        else ((float*)out)[idx] = vvv;
      }
    }
  }
}

// ---------------- fused causal flash attention v2 ----------------
// qkv: (B,T,768) bf16 rows = [q(8x32) k(8x32) v(8x32)]; o: (B,T,256) bf16
// Block: 4 waves x 32 q-rows = 128 q/block. KV tiles of 64.
// S^T = mfma(K,Q) so q sits on lanes: 2-round row reduce + ds_write_b64 P.
__global__ __launch_bounds__(256, 4) void k_attn(const unsigned short* __restrict__ qkv,
                                                 unsigned short* __restrict__ o) {
  __shared__ __align__(16) unsigned short Ks[64 * 32];       // [k][32] linear (gload_lds)
  __shared__ __align__(16) unsigned short Vs[32 * 72];       // [d][k ^ ((d>>3)<<4)]
  __shared__ __align__(16) unsigned short Ps[4][32 * 72];    // per-wave P [qlocal][k]
  const int tid = threadIdx.x, lane = tid & 63, w = tid >> 6;
  const int l15 = lane & 15, g = lane >> 4;
  const int qt = blockIdx.x;
  const int b = blockIdx.y >> 3, hh = blockIdx.y & 7;
  const size_t base = (size_t)b * TT * 768;
  const int q0 = qt * 128 + w * 32;
  s16x8 qf[2];
#pragma unroll
  for (int qg = 0; qg < 2; ++qg)
    qf[qg] = *(const s16x8*)(qkv + base + (size_t)(q0 + qg * 16 + l15) * 768 + hh * 32 + g * 8);
  f32x4 accO[2][2] = {};  // [qg][hb]: rows q=g*4+r, col d=hb*16+l15
  float mM[2] = {-3.0e38f, -3.0e38f}, ls[2] = {0.f, 0.f};
  const int krow = tid >> 2, kpart = tid & 3;
  const float scl = 0.17677669529663687f;  // 1/sqrt(32)
  const int nj = 2 * (qt + 1);
  unsigned short* Pw = &Ps[w][0];
  for (int j = 0; j < nj; ++j) {
    const size_t srow = base + (size_t)(j * 64 + krow) * 768 + hh * 32;
    gload16(qkv + srow + 256 + kpart * 8, Ks + tid * 8);
    s16x8 vv = *(const s16x8*)(qkv + srow + 512 + kpart * 8);
    const int kx = krow ^ (kpart << 4);
#pragma unroll
    for (int e = 0; e < 8; ++e) Vs[(kpart * 8 + e) * 72 + kx] = (unsigned short)vv[e];
    __syncthreads();
    if (j * 64 <= q0 + 31) {
      s16x8 kfr[4];
#pragma unroll
      for (int cb = 0; cb < 4; ++cb)
        kfr[cb] = *(const s16x8*)(Ks + (cb * 16 + l15) * 32 + g * 8);
      const bool full = (j * 64 + 63 <= q0);
      float al2[2];
#pragma unroll
      for (int qg = 0; qg < 2; ++qg) {
        f32x4 st[4];
#pragma unroll
        for (int cb = 0; cb < 4; ++cb) {
          f32x4 zz = {};
          st[cb] = __builtin_amdgcn_mfma_f32_16x16x32_bf16(kfr[cb], qf[qg], zz, 0, 0, 0);
        }
        const int qglob = q0 + qg * 16 + l15;
        float rmax = -3.0e38f;
#pragma unroll
        for (int cb = 0; cb < 4; ++cb)
#pragma unroll
          for (int r = 0; r < 4; ++r) {
            float s = st[cb][r] * scl;
            if (!full && (j * 64 + cb * 16 + g * 4 + r) > qglob) s = -3.0e38f;
            st[cb][r] = s;
            rmax = fmaxf(rmax, s);
          }
        rmax = fmaxf(rmax, __shfl_xor(rmax, 16));
        rmax = fmaxf(rmax, __shfl_xor(rmax, 32));
        float nm = fmaxf(mM[qg], rmax);
        al2[qg] = __expf(mM[qg] - nm);
        mM[qg] = nm;
        float rsum = 0.f;
#pragma unroll
        for (int cb = 0; cb < 4; ++cb) {
          union { unsigned short us[4]; unsigned long long u; } pk;
#pragma unroll
          for (int r = 0; r < 4; ++r) {
            float p = __expf(st[cb][r] - nm);
            rsum += p;
            pk.us[r] = f2bf(p);
          }
          *(unsigned long long*)(Pw + (qg * 16 + l15) * 72 + cb * 16 + g * 4) = pk.u;
        }
        rsum += __shfl_xor(rsum, 16);
        rsum += __shfl_xor(rsum, 32);
        ls[qg] = ls[qg] * al2[qg] + rsum;
      }
      // rescale running O by al (broadcast from lane q = g*4+r)
#pragma unroll
      for (int qg = 0; qg < 2; ++qg)
#pragma unroll
        for (int r = 0; r < 4; ++r) {
          float aw = __shfl(al2[qg], g * 4 + r);
#pragma unroll
          for (int hb = 0; hb < 2; ++hb) accO[qg][hb][r] *= aw;
        }
      asm volatile("s_waitcnt lgkmcnt(0)" ::: "memory");
      __builtin_amdgcn_sched_barrier(0);
#pragma unroll
      for (int ks = 0; ks < 2; ++ks) {
        s16x8 pa[2], bv[2];
#pragma unroll
        for (int qg = 0; qg < 2; ++qg)
          pa[qg] = *(const s16x8*)(Pw + (qg * 16 + l15) * 72 + ks * 32 + g * 8);
#pragma unroll
        for (int hb = 0; hb < 2; ++hb) {
          const int d = hb * 16 + l15;
          const int kxr = (ks * 32 + g * 8) ^ (((d >> 3) & 3) << 4);
          bv[hb] = *(const s16x8*)(Vs + d * 72 + kxr);
        }
#pragma unroll
        for (int qg = 0; qg < 2; ++qg)
#pragma unroll
          for (int hb = 0; hb < 2; ++hb)
            accO[qg][hb] = __builtin_amdgcn_mfma_f32_16x16x32_bf16(pa[qg], bv[hb], accO[qg][hb], 0, 0, 0);
      }
    }
    __syncthreads();
  }
#pragma unroll
  for (int qg = 0; qg < 2; ++qg) {
    float inv = 1.0f / ls[qg];
#pragma unroll
    for (int r = 0; r < 4; ++r) {
      float lv = __shfl(inv, g * 4 + r);
      int row = q0 + qg * 16 + g * 4 + r;
#pragma unroll
      for (int hb = 0; hb < 2; ++hb)
        o[(size_t)(b * TT + row) * DD + hh * 32 + hb * 16 + l15] = f2bf(accO[qg][hb][r] * lv);
    }
  }
}

extern "C" void kernel_launch(void* const* d_in, const int* in_sizes, int n_in,
                              void* d_out, int out_size, void* d_ws, size_t ws_size,
                              hipStream_t stream) {
  const int* x = (const int*)d_in[0];
  const float* tok = (const float*)d_in[1];
  const float* pos = (const float*)d_in[2];
  const float* ln1w = (const float*)d_in[3];
  const float* ln1b = (const float*)d_in[4];
  const float* qkvw = (const float*)d_in[5];
  const float* qkvb = (const float*)d_in[6];
  const float* outw = (const float*)d_in[7];
  const float* outb = (const float*)d_in[8];
  const float* ln2w = (const float*)d_in[9];
  const float* ln2b = (const float*)d_in[10];
  const float* f1w = (const float*)d_in[11];
  const float* f1b = (const float*)d_in[12];
  const float* f2w = (const float*)d_in[13];
  const float* f2b = (const float*)d_in[14];
  const float* lnfw = (const float*)d_in[15];
  const float* lnfb = (const float*)d_in[16];
  const float* hw = (const float*)d_in[17];
  const float* hb = (const float*)d_in[18];

  char* ws = (char*)d_ws;
  float* h = (float*)(ws + 0);                                  //  8 MB
  unsigned short* z = (unsigned short*)(ws + 8388608);          //  4 MB
  unsigned short* qkvB = (unsigned short*)(ws + 12582912);      // 12 MB
  unsigned short* ob = (unsigned short*)(ws + 25165824);        //  4 MB
  unsigned short* a1 = (unsigned short*)(ws + 29360128);        // 16 MB
  unsigned short* wq = (unsigned short*)(ws + 46137344);
  unsigned short* wo = (unsigned short*)(ws + 46530560);
  unsigned short* w1 = (unsigned short*)(ws + 46661632);
  unsigned short* w2 = (unsigned short*)(ws + 47185920);
  unsigned short* wh = (unsigned short*)(ws + 47710208);        // end ~47.9 MB

  k_cast_tr256<<<dim3(256), dim3(256), 0, stream>>>(hw, wh);
  k_embed<<<dim3(2048), dim3(256), 0, stream>>>(x, tok, pos, h);

  for (int l = 0; l < LL; ++l) {
    k_cast_tr4<<<dim3(1024), dim3(256), 0, stream>>>(
        qkvw + (size_t)l * 256 * 768, outw + (size_t)l * 256 * 256,
        f1w + (size_t)l * 256 * 1024, f2w + (size_t)l * 1024 * 256, wq, wo, w1, w2);
    k_ln<<<dim3(2048), dim3(256), 0, stream>>>(h, ln1w + l * 256, ln1b + l * 256, z);
    k_gemm<0, 4><<<dim3(6, 64), dim3(256), 0, stream>>>(z, wq, qkvb + l * 768, qkvB, nullptr, 8192, 768, 256);
    k_attn<<<dim3(16, 32), dim3(256), 0, stream>>>(qkvB, ob);
    k_gemm<2, 2><<<dim3(2, 128), dim3(256), 0, stream>>>(ob, wo, outb + l * 256, h, h, 8192, 256, 256);
    k_ln<<<dim3(2048), dim3(256), 0, stream>>>(h, ln2w + l * 256, ln2b + l * 256, z);
    k_gemm<1, 4><<<dim3(8, 64), dim3(256), 0, stream>>>(z, w1, f1b + l * 1024, a1, nullptr, 8192, 1024, 256);
    k_gemm<2, 2><<<dim3(2, 128), dim3(256), 0, stream>>>(a1, w2, f2b + l * 256, h, h, 8192, 256, 1024);
  }

  k_ln<<<dim3(2048), dim3(256), 0, stream>>>(h, lnfw, lnfb, z);
  k_gemm<3, 2><<<dim3(2, 128), dim3(256), 0, stream>>>(z, wh, hb, d_out, nullptr, 8192, 256, 256);
}

// Round 4
// 1837.451 us; speedup vs baseline: 1.2534x; 1.0413x over previous
//
#include <hip/hip_runtime.h>
#include <cstdint>

#define TT 2048
#define DD 256
#define HH 8
#define LL 12

typedef __attribute__((ext_vector_type(8))) short s16x8;
typedef __attribute__((ext_vector_type(4))) float f32x4;

__device__ __forceinline__ unsigned short f2bf(float f) {
  union { float f; unsigned u; } v; v.f = f;
  return (unsigned short)((v.u + 0x7FFFu + ((v.u >> 16) & 1u)) >> 16);
}

__device__ __forceinline__ float geluf(float x) {
  return 0.5f * x * (1.0f + erff(x * 0.70710678118654752f));
}

__device__ __forceinline__ void gload16(const void* g, void* l) {
  __builtin_amdgcn_global_load_lds((const __attribute__((address_space(1))) unsigned int*)g,
                                   (__attribute__((address_space(3))) unsigned int*)l, 16, 0, 0);
}

// ---------------- embedding: h = tok[x] + pos ----------------
__global__ __launch_bounds__(256) void k_embed(const int* __restrict__ x,
                                               const float* __restrict__ tok,
                                               const float* __restrict__ pos,
                                               float* __restrict__ h) {
  int i = blockIdx.x * 256 + threadIdx.x;  // vec4 index, total 8192*64
  int row = i >> 6, c = i & 63;
  int t = x[row];
  f32x4 tv = ((const f32x4*)(tok + (size_t)t * DD))[c];
  f32x4 pv = ((const f32x4*)(pos + (size_t)(row & (TT - 1)) * DD))[c];
  ((f32x4*)(h + (size_t)row * DD))[c] = tv + pv;
}

// ---------------- layernorm (f32 in) -> bf16 out ----------------
__global__ __launch_bounds__(256) void k_ln(const float* __restrict__ h,
                                            const float* __restrict__ wgt,
                                            const float* __restrict__ bia,
                                            unsigned short* __restrict__ z) {
  int row = blockIdx.x * 4 + (threadIdx.x >> 6);
  int lane = threadIdx.x & 63;
  f32x4 v = ((const f32x4*)(h + (size_t)row * DD))[lane];
  float s = v[0] + v[1] + v[2] + v[3];
#pragma unroll
  for (int m = 32; m; m >>= 1) s += __shfl_xor(s, m);
  float mean = s * (1.0f / DD);
  f32x4 d = v - mean;
  float s2 = d[0] * d[0] + d[1] * d[1] + d[2] * d[2] + d[3] * d[3];
#pragma unroll
  for (int m = 32; m; m >>= 1) s2 += __shfl_xor(s2, m);
  float inv = rsqrtf(s2 * (1.0f / DD) + 1e-5f);
  f32x4 wv = ((const f32x4*)wgt)[lane];
  f32x4 bv = ((const f32x4*)bia)[lane];
  union { unsigned short us[4]; unsigned long long u64; } ou;
#pragma unroll
  for (int e = 0; e < 4; ++e) ou.us[e] = f2bf(d[e] * inv * wv[e] + bv[e]);
  *(unsigned long long*)(z + (size_t)row * DD + lane * 4) = ou.u64;
}

// ---------------- weight cast+transpose f32 (K,N) -> bf16 (N,K) ----------------
__global__ __launch_bounds__(256) void k_cast_tr4(const float* __restrict__ qw, const float* __restrict__ ow,
                                                  const float* __restrict__ f1, const float* __restrict__ f2,
                                                  unsigned short* __restrict__ dq, unsigned short* __restrict__ dO,
                                                  unsigned short* __restrict__ d1, unsigned short* __restrict__ d2) {
  int t0 = blockIdx.x * 256 + threadIdx.x;
  int stride = gridDim.x * 256;
  for (int i = t0; i < 256 * 768; i += stride) { int k = i / 768, n = i % 768; dq[n * 256 + k] = f2bf(qw[i]); }
  for (int i = t0; i < 256 * 256; i += stride) { int k = i >> 8, n = i & 255; dO[n * 256 + k] = f2bf(ow[i]); }
  for (int i = t0; i < 256 * 1024; i += stride) { int k = i >> 10, n = i & 1023; d1[n * 256 + k] = f2bf(f1[i]); }
  for (int i = t0; i < 1024 * 256; i += stride) { int k = i >> 8, n = i & 255; d2[n * 1024 + k] = f2bf(f2[i]); }
}

__global__ __launch_bounds__(256) void k_cast_tr256(const float* __restrict__ src, unsigned short* __restrict__ dst) {
  int i = blockIdx.x * 256 + threadIdx.x;  // 256x256
  int k = i >> 8, n = i & 255;
  dst[n * 256 + k] = f2bf(src[i]);
}

// ---------------- GEMM: C[M,N] = A[M,K](bf16) * BT[N,K]^T(bf16) + bias ----------------
// MODE 0: bf16 store; 1: gelu->bf16; 2: f32 resid+store; 3: f32 store
template <int MODE, int MI>
__global__ __launch_bounds__(256) void k_gemm(const unsigned short* __restrict__ A,
                                              const unsigned short* __restrict__ BT,
                                              const float* __restrict__ bias,
                                              void* out, const float* resid,
                                              int M, int N, int K) {
  __shared__ __align__(16) unsigned short As[MI * 32 * 64];
  __shared__ __align__(16) unsigned short Bs[128 * 64];
  const int tid = threadIdx.x;
  const int lane = tid & 63, wv = tid >> 6;
  const int wr = wv >> 1, wc = wv & 1;
  const int l15 = lane & 15, g = lane >> 4;
  const int BM = MI * 32;
  const int tm = blockIdx.y, tn = blockIdx.x;
  f32x4 acc[MI][4] = {};
  const int nk = K >> 6;
  const unsigned short* Ag0 = A + (size_t)tm * BM * K;
  const unsigned short* Bg0 = BT + (size_t)tn * 128 * K;
  for (int kt = 0; kt < nk; ++kt) {
#pragma unroll
    for (int it = 0; it < MI; ++it) {
      int chunk = it * 256 + tid;
      int row = chunk >> 3, part = chunk & 7;
      gload16(Ag0 + (size_t)row * K + kt * 64 + part * 8, As + chunk * 8);
    }
#pragma unroll
    for (int it = 0; it < 4; ++it) {
      int chunk = it * 256 + tid;
      int row = chunk >> 3, part = chunk & 7;
      gload16(Bg0 + (size_t)row * K + kt * 64 + part * 8, Bs + chunk * 8);
    }
    __syncthreads();
#pragma unroll
    for (int ks = 0; ks < 2; ++ks) {
      s16x8 af[MI], bf[4];
#pragma unroll
      for (int mi = 0; mi < MI; ++mi)
        af[mi] = *(const s16x8*)(As + (wr * MI * 16 + mi * 16 + l15) * 64 + ks * 32 + g * 8);
#pragma unroll
      for (int ni = 0; ni < 4; ++ni)
        bf[ni] = *(const s16x8*)(Bs + (wc * 64 + ni * 16 + l15) * 64 + ks * 32 + g * 8);
#pragma unroll
      for (int mi = 0; mi < MI; ++mi)
#pragma unroll
        for (int ni = 0; ni < 4; ++ni)
          acc[mi][ni] = __builtin_amdgcn_mfma_f32_16x16x32_bf16(af[mi], bf[ni], acc[mi][ni], 0, 0, 0);
    }
    __syncthreads();
  }
#pragma unroll
  for (int ni = 0; ni < 4; ++ni) {
    int col = tn * 128 + wc * 64 + ni * 16 + l15;
    float bv = bias[col];
#pragma unroll
    for (int mi = 0; mi < MI; ++mi) {
      int row0 = tm * BM + wr * MI * 16 + mi * 16 + g * 4;
#pragma unroll
      for (int r = 0; r < 4; ++r) {
        size_t idx = (size_t)(row0 + r) * N + col;
        float vvv = acc[mi][ni][r] + bv;
        if (MODE == 0) ((unsigned short*)out)[idx] = f2bf(vvv);
        else if (MODE == 1) ((unsigned short*)out)[idx] = f2bf(geluf(vvv));
        else if (MODE == 2) ((float*)out)[idx] = resid[idx] + vvv;
        else ((float*)out)[idx] = vvv;
      }
    }
  }
}

// ---------------- fused causal flash attention v3 ----------------
// Paired q-tiles (p, 15-p) of 128 q each -> 17 KV-tiles (128 keys) per block,
// perfectly balanced. Double-buffered K/V staging pipelined under compute.
__global__ __launch_bounds__(256, 2) void k_attn(const unsigned short* __restrict__ qkv,
                                                 unsigned short* __restrict__ o) {
  __shared__ __align__(16) unsigned short Ks[2][128 * 32];     // [buf][k][32d] linear
  __shared__ __align__(16) unsigned short Vs[2][2 * 32 * 72];  // [buf][khalf][d][klo^swz]
  __shared__ __align__(16) unsigned short Ps[4][2 * 32 * 72];  // [wave][khalf][q][k']
  const int tid = threadIdx.x, lane = tid & 63, w = tid >> 6;
  const int l15 = lane & 15, g = lane >> 4;
  const int p = blockIdx.x;                       // 0..7
  const int b = blockIdx.y >> 3, hh = blockIdx.y & 7;
  const size_t base = (size_t)b * TT * 768 + hh * 32;
  const float scl = 0.17677669529663687f;         // 1/sqrt(32)
  const int vk = tid & 127, vdh = tid >> 7;       // V stage mapping
  const int vkhalf = vk >> 6, vklo = vk & 63;
  unsigned short* Pw = &Ps[w][0];

  const int qt0 = p, qt1 = 15 - p;
  // Q fragments for both phases
  s16x8 qfA[2], qfB[2];
#pragma unroll
  for (int qg = 0; qg < 2; ++qg) {
    qfA[qg] = *(const s16x8*)(qkv + base + (size_t)(qt0 * 128 + w * 32 + qg * 16 + l15) * 768 + g * 8);
    qfB[qg] = *(const s16x8*)(qkv + base + (size_t)(qt1 * 128 + w * 32 + qg * 16 + l15) * 768 + g * 8);
  }

  // ---- stage tile 0 (phase 0, j=0) into buf 0
  {
    const unsigned short* ksrc = qkv + base + 256;
#pragma unroll
    for (int i = 0; i < 2; ++i)
      gload16(ksrc + (size_t)(i * 64 + (tid >> 2)) * 768 + (tid & 3) * 8, Ks[0] + i * 2048 + tid * 8);
    const unsigned short* vsrc = qkv + base + (size_t)vk * 768 + 512 + vdh * 16;
    s16x8 vA = *(const s16x8*)(vsrc);
    s16x8 vB = *(const s16x8*)(vsrc + 8);
    unsigned short* vb = Vs[0] + vkhalf * 2304;
#pragma unroll
    for (int e = 0; e < 8; ++e) {
      int d0 = vdh * 16 + e, d1 = vdh * 16 + 8 + e;
      vb[d0 * 72 + (vklo ^ (((d0 >> 3) & 3) << 4))] = (unsigned short)vA[e];
      vb[d1 * 72 + (vklo ^ (((d1 >> 3) & 3) << 4))] = (unsigned short)vB[e];
    }
  }
  __syncthreads();

  f32x4 accO[2][2] = {};
  float mM[2] = {-3.0e38f, -3.0e38f}, ls2[2] = {0.f, 0.f};

  for (int t = 0; t < 17; ++t) {
    const int phase = (t > p);
    const int qt = phase ? qt1 : qt0;
    const int j = phase ? t - p - 1 : t;
    const int buf = t & 1;
    const bool have_next = (t + 1 < 17);
    s16x8 vA, vB;
    if (have_next) {
      const int jn = (t + 1 > p) ? t - p : t + 1;
      const size_t krow = base + (size_t)(jn * 128) * 768;
#pragma unroll
      for (int i = 0; i < 2; ++i)
        gload16(qkv + krow + (size_t)(i * 64 + (tid >> 2)) * 768 + 256 + (tid & 3) * 8,
                Ks[buf ^ 1] + i * 2048 + tid * 8);
      const unsigned short* vsrc = qkv + krow + (size_t)vk * 768 + 512 + vdh * 16;
      vA = *(const s16x8*)(vsrc);
      vB = *(const s16x8*)(vsrc + 8);
    }
    // ---------- compute tile (qt, j) from buf ----------
    const bool diag = (j == qt);
    const int q0 = qt * 128 + w * 32;
    const int cbmax = diag ? 2 * w + 1 : 7;
    const int kcmax = diag ? w : 3;
    s16x8 kfr[8];
#pragma unroll
    for (int cb = 0; cb < 8; ++cb)
      if (cb <= cbmax)
        kfr[cb] = *(const s16x8*)(Ks[buf] + (cb * 16 + l15) * 32 + g * 8);
    float al2[2];
#pragma unroll
    for (int qg = 0; qg < 2; ++qg) {
      s16x8 qf = phase ? qfB[qg] : qfA[qg];
      f32x4 st[8];
#pragma unroll
      for (int cb = 0; cb < 8; ++cb)
        if (cb <= cbmax) {
          f32x4 zz = {};
          st[cb] = __builtin_amdgcn_mfma_f32_16x16x32_bf16(kfr[cb], qf, zz, 0, 0, 0);
        }
      const int qglob = q0 + qg * 16 + l15;
      float rmax = -3.0e38f;
#pragma unroll
      for (int cb = 0; cb < 8; ++cb)
        if (cb <= cbmax) {
#pragma unroll
          for (int r = 0; r < 4; ++r) {
            float s = st[cb][r] * scl;
            if (diag && (j * 128 + cb * 16 + g * 4 + r) > qglob) s = -3.0e38f;
            st[cb][r] = s;
            rmax = fmaxf(rmax, s);
          }
        }
      rmax = fmaxf(rmax, __shfl_xor(rmax, 16));
      rmax = fmaxf(rmax, __shfl_xor(rmax, 32));
      float nm = fmaxf(mM[qg], rmax);
      al2[qg] = __expf(mM[qg] - nm);
      mM[qg] = nm;
      float rsum = 0.f;
#pragma unroll
      for (int cb = 0; cb < 8; ++cb)
        if (cb <= cbmax) {
          union { unsigned short us[4]; unsigned long long u; } pk;
#pragma unroll
          for (int r = 0; r < 4; ++r) {
            float pe = __expf(st[cb][r] - nm);
            rsum += pe;
            pk.us[r] = f2bf(pe);
          }
          *(unsigned long long*)(Pw + (cb >> 2) * 2304 + (qg * 16 + l15) * 72 + (cb & 3) * 16 + g * 4) = pk.u;
        }
      rsum += __shfl_xor(rsum, 16);
      rsum += __shfl_xor(rsum, 32);
      ls2[qg] = ls2[qg] * al2[qg] + rsum;
    }
#pragma unroll
    for (int qg = 0; qg < 2; ++qg)
#pragma unroll
      for (int r = 0; r < 4; ++r) {
        float aw = __shfl(al2[qg], g * 4 + r);
        accO[qg][0][r] *= aw;
        accO[qg][1][r] *= aw;
      }
    asm volatile("s_waitcnt lgkmcnt(0)" ::: "memory");
    __builtin_amdgcn_sched_barrier(0);
#pragma unroll
    for (int kc = 0; kc < 4; ++kc)
      if (kc <= kcmax) {
        s16x8 pa0 = *(const s16x8*)(Pw + (kc >> 1) * 2304 + l15 * 72 + (kc & 1) * 32 + g * 8);
        s16x8 pa1 = *(const s16x8*)(Pw + (kc >> 1) * 2304 + (16 + l15) * 72 + (kc & 1) * 32 + g * 8);
        s16x8 bv[2];
#pragma unroll
        for (int hb = 0; hb < 2; ++hb) {
          const int d = hb * 16 + l15;
          const int kxr = ((kc & 1) * 32 + g * 8) ^ (((d >> 3) & 3) << 4);
          bv[hb] = *(const s16x8*)(Vs[buf] + (kc >> 1) * 2304 + d * 72 + kxr);
        }
        accO[0][0] = __builtin_amdgcn_mfma_f32_16x16x32_bf16(pa0, bv[0], accO[0][0], 0, 0, 0);
        accO[0][1] = __builtin_amdgcn_mfma_f32_16x16x32_bf16(pa0, bv[1], accO[0][1], 0, 0, 0);
        accO[1][0] = __builtin_amdgcn_mfma_f32_16x16x32_bf16(pa1, bv[0], accO[1][0], 0, 0, 0);
        accO[1][1] = __builtin_amdgcn_mfma_f32_16x16x32_bf16(pa1, bv[1], accO[1][1], 0, 0, 0);
      }
    // ---------- V^T write for next tile, then barrier ----------
    if (have_next) {
      unsigned short* vb = Vs[buf ^ 1] + vkhalf * 2304;
#pragma unroll
      for (int e = 0; e < 8; ++e) {
        int d0 = vdh * 16 + e, d1 = vdh * 16 + 8 + e;
        vb[d0 * 72 + (vklo ^ (((d0 >> 3) & 3) << 4))] = (unsigned short)vA[e];
        vb[d1 * 72 + (vklo ^ (((d1 >> 3) & 3) << 4))] = (unsigned short)vB[e];
      }
    }
    __syncthreads();
    if (t == p) {  // phase 0 finished: write O for qt0, reset state
#pragma unroll
      for (int qg = 0; qg < 2; ++qg) {
        float inv = 1.0f / ls2[qg];
#pragma unroll
        for (int r = 0; r < 4; ++r) {
          float lv = __shfl(inv, g * 4 + r);
          int row = qt0 * 128 + w * 32 + qg * 16 + g * 4 + r;
#pragma unroll
          for (int hb = 0; hb < 2; ++hb)
            o[(size_t)(b * TT + row) * DD + hh * 32 + hb * 16 + l15] = f2bf(accO[qg][hb][r] * lv);
        }
        accO[qg][0] = f32x4{};
        accO[qg][1] = f32x4{};
        mM[qg] = -3.0e38f;
        ls2[qg] = 0.f;
      }
    }
  }
#pragma unroll
  for (int qg = 0; qg < 2; ++qg) {
    float inv = 1.0f / ls2[qg];
#pragma unroll
    for (int r = 0; r < 4; ++r) {
      float lv = __shfl(inv, g * 4 + r);
      int row = qt1 * 128 + w * 32 + qg * 16 + g * 4 + r;
#pragma unroll
      for (int hb = 0; hb < 2; ++hb)
        o[(size_t)(b * TT + row) * DD + hh * 32 + hb * 16 + l15] = f2bf(accO[qg][hb][r] * lv);
    }
  }
}

extern "C" void kernel_launch(void* const* d_in, const int* in_sizes, int n_in,
                              void* d_out, int out_size, void* d_ws, size_t ws_size,
                              hipStream_t stream) {
  const int* x = (const int*)d_in[0];
  const float* tok = (const float*)d_in[1];
  const float* pos = (const float*)d_in[2];
  const float* ln1w = (const float*)d_in[3];
  const float* ln1b = (const float*)d_in[4];
  const float* qkvw = (const float*)d_in[5];
  const float* qkvb = (const float*)d_in[6];
  const float* outw = (const float*)d_in[7];
  const float* outb = (const float*)d_in[8];
  const float* ln2w = (const float*)d_in[9];
  const float* ln2b = (const float*)d_in[10];
  const float* f1w = (const float*)d_in[11];
  const float* f1b = (const float*)d_in[12];
  const float* f2w = (const float*)d_in[13];
  const float* f2b = (const float*)d_in[14];
  const float* lnfw = (const float*)d_in[15];
  const float* lnfb = (const float*)d_in[16];
  const float* hw = (const float*)d_in[17];
  const float* hb = (const float*)d_in[18];

  char* ws = (char*)d_ws;
  float* h = (float*)(ws + 0);                                  //  8 MB
  unsigned short* z = (unsigned short*)(ws + 8388608);          //  4 MB
  unsigned short* qkvB = (unsigned short*)(ws + 12582912);      // 12 MB
  unsigned short* ob = (unsigned short*)(ws + 25165824);        //  4 MB
  unsigned short* a1 = (unsigned short*)(ws + 29360128);        // 16 MB
  unsigned short* wq = (unsigned short*)(ws + 46137344);
  unsigned short* wo = (unsigned short*)(ws + 46530560);
  unsigned short* w1 = (unsigned short*)(ws + 46661632);
  unsigned short* w2 = (unsigned short*)(ws + 47185920);
  unsigned short* wh = (unsigned short*)(ws + 47710208);        // end ~47.9 MB

  k_cast_tr256<<<dim3(256), dim3(256), 0, stream>>>(hw, wh);
  k_embed<<<dim3(2048), dim3(256), 0, stream>>>(x, tok, pos, h);

  for (int l = 0; l < LL; ++l) {
    k_cast_tr4<<<dim3(1024), dim3(256), 0, stream>>>(
        qkvw + (size_t)l * 256 * 768, outw + (size_t)l * 256 * 256,
        f1w + (size_t)l * 256 * 1024, f2w + (size_t)l * 1024 * 256, wq, wo, w1, w2);
    k_ln<<<dim3(2048), dim3(256), 0, stream>>>(h, ln1w + l * 256, ln1b + l * 256, z);
    k_gemm<0, 4><<<dim3(6, 64), dim3(256), 0, stream>>>(z, wq, qkvb + l * 768, qkvB, nullptr, 8192, 768, 256);
    k_attn<<<dim3(8, 32), dim3(256), 0, stream>>>(qkvB, ob);
    k_gemm<2, 2><<<dim3(2, 128), dim3(256), 0, stream>>>(ob, wo, outb + l * 256, h, h, 8192, 256, 256);
    k_ln<<<dim3(2048), dim3(256), 0, stream>>>(h, ln2w + l * 256, ln2b + l * 256, z);
    k_gemm<1, 4><<<dim3(8, 64), dim3(256), 0, stream>>>(z, w1, f1b + l * 1024, a1, nullptr, 8192, 1024, 256);
    k_gemm<2, 2><<<dim3(2, 128), dim3(256), 0, stream>>>(a1, w2, f2b + l * 256, h, h, 8192, 256, 1024);
  }

  k_ln<<<dim3(2048), dim3(256), 0, stream>>>(h, lnfw, lnfb, z);
  k_gemm<3, 2><<<dim3(2, 128), dim3(256), 0, stream>>>(z, wh, hb, d_out, nullptr, 8192, 256, 256);
}

// Round 6
// 1544.113 us; speedup vs baseline: 1.4915x; 1.1900x over previous
//
#include <hip/hip_runtime.h>
#include <cstdint>

#define TT 2048
#define DD 256
#define HH 8
#define LL 12

typedef __attribute__((ext_vector_type(8))) short s16x8;
typedef __attribute__((ext_vector_type(4))) float f32x4;

__device__ __forceinline__ unsigned short f2bf(float f) {
  union { float f; unsigned u; } v; v.f = f;
  return (unsigned short)((v.u + 0x7FFFu + ((v.u >> 16) & 1u)) >> 16);
}

__device__ __forceinline__ float geluf(float x) {
  return 0.5f * x * (1.0f + erff(x * 0.70710678118654752f));
}

__device__ __forceinline__ float fexp2(float x) {
  float r;
  asm("v_exp_f32 %0, %1" : "=v"(r) : "v"(x));
  return r;
}

__device__ __forceinline__ void gload16(const void* g, void* l) {
  __builtin_amdgcn_global_load_lds((const __attribute__((address_space(1))) unsigned int*)g,
                                   (__attribute__((address_space(3))) unsigned int*)l, 16, 0, 0);
}

// ---------------- embedding: h = tok[x] + pos ----------------
__global__ __launch_bounds__(256) void k_embed(const int* __restrict__ x,
                                               const float* __restrict__ tok,
                                               const float* __restrict__ pos,
                                               float* __restrict__ h) {
  int i = blockIdx.x * 256 + threadIdx.x;  // vec4 index, total 8192*64
  int row = i >> 6, c = i & 63;
  int t = x[row];
  f32x4 tv = ((const f32x4*)(tok + (size_t)t * DD))[c];
  f32x4 pv = ((const f32x4*)(pos + (size_t)(row & (TT - 1)) * DD))[c];
  ((f32x4*)(h + (size_t)row * DD))[c] = tv + pv;
}

// ---------------- layernorm (f32 in) -> bf16 out ----------------
__global__ __launch_bounds__(256) void k_ln(const float* __restrict__ h,
                                            const float* __restrict__ wgt,
                                            const float* __restrict__ bia,
                                            unsigned short* __restrict__ z) {
  int row = blockIdx.x * 4 + (threadIdx.x >> 6);
  int lane = threadIdx.x & 63;
  f32x4 v = ((const f32x4*)(h + (size_t)row * DD))[lane];
  float s = v[0] + v[1] + v[2] + v[3];
#pragma unroll
  for (int m = 32; m; m >>= 1) s += __shfl_xor(s, m);
  float mean = s * (1.0f / DD);
  f32x4 d = v - mean;
  float s2 = d[0] * d[0] + d[1] * d[1] + d[2] * d[2] + d[3] * d[3];
#pragma unroll
  for (int m = 32; m; m >>= 1) s2 += __shfl_xor(s2, m);
  float inv = rsqrtf(s2 * (1.0f / DD) + 1e-5f);
  f32x4 wv = ((const f32x4*)wgt)[lane];
  f32x4 bv = ((const f32x4*)bia)[lane];
  union { unsigned short us[4]; unsigned long long u64; } ou;
#pragma unroll
  for (int e = 0; e < 4; ++e) ou.us[e] = f2bf(d[e] * inv * wv[e] + bv[e]);
  *(unsigned long long*)(z + (size_t)row * DD + lane * 4) = ou.u64;
}

// ---------------- weight cast+transpose: all layers in one launch ----------------
__global__ __launch_bounds__(256) void k_cast_all(const float* __restrict__ qw, const float* __restrict__ ow,
                                                  const float* __restrict__ f1, const float* __restrict__ f2,
                                                  unsigned short* __restrict__ dst) {
  const int l = blockIdx.y;
  const int t0 = blockIdx.x * 256 + threadIdx.x;
  const int stride = gridDim.x * 256;
  const float* qwl = qw + (size_t)l * 196608;
  const float* owl = ow + (size_t)l * 65536;
  const float* f1l = f1 + (size_t)l * 262144;
  const float* f2l = f2 + (size_t)l * 262144;
  unsigned short* dq = dst + (size_t)l * 786432;
  unsigned short* dO = dq + 196608;
  unsigned short* d1 = dO + 65536;
  unsigned short* d2 = d1 + 262144;
  for (int i = t0; i < 196608; i += stride) { int k = i / 768, n = i % 768; dq[n * 256 + k] = f2bf(qwl[i]); }
  for (int i = t0; i < 65536; i += stride) { int k = i >> 8, n = i & 255; dO[n * 256 + k] = f2bf(owl[i]); }
  for (int i = t0; i < 262144; i += stride) { int k = i >> 10, n = i & 1023; d1[n * 256 + k] = f2bf(f1l[i]); }
  for (int i = t0; i < 262144; i += stride) { int k = i >> 8, n = i & 255; d2[n * 1024 + k] = f2bf(f2l[i]); }
}

// per-layer fallback (small ws)
__global__ __launch_bounds__(256) void k_cast_tr4(const float* __restrict__ qw, const float* __restrict__ ow,
                                                  const float* __restrict__ f1, const float* __restrict__ f2,
                                                  unsigned short* __restrict__ dq, unsigned short* __restrict__ dO,
                                                  unsigned short* __restrict__ d1, unsigned short* __restrict__ d2) {
  int t0 = blockIdx.x * 256 + threadIdx.x;
  int stride = gridDim.x * 256;
  for (int i = t0; i < 256 * 768; i += stride) { int k = i / 768, n = i % 768; dq[n * 256 + k] = f2bf(qw[i]); }
  for (int i = t0; i < 256 * 256; i += stride) { int k = i >> 8, n = i & 255; dO[n * 256 + k] = f2bf(ow[i]); }
  for (int i = t0; i < 256 * 1024; i += stride) { int k = i >> 10, n = i & 1023; d1[n * 256 + k] = f2bf(f1[i]); }
  for (int i = t0; i < 1024 * 256; i += stride) { int k = i >> 8, n = i & 255; d2[n * 1024 + k] = f2bf(f2[i]); }
}

__global__ __launch_bounds__(256) void k_cast_tr256(const float* __restrict__ src, unsigned short* __restrict__ dst) {
  int i = blockIdx.x * 256 + threadIdx.x;  // 256x256
  int k = i >> 8, n = i & 255;
  dst[n * 256 + k] = f2bf(src[i]);
}

// ---------------- GEMM: C[M,N] = A[M,K](bf16) * BT[N,K]^T(bf16) + bias ----------------
// MODE 0: bf16 store; 1: gelu->bf16; 2: f32 resid+store; 3: f32 store
template <int MODE, int MI>
__global__ __launch_bounds__(256) void k_gemm(const unsigned short* __restrict__ A,
                                              const unsigned short* __restrict__ BT,
                                              const float* __restrict__ bias,
                                              void* out, const float* resid,
                                              int M, int N, int K) {
  __shared__ __align__(16) unsigned short As[MI * 32 * 64];
  __shared__ __align__(16) unsigned short Bs[128 * 64];
  const int tid = threadIdx.x;
  const int lane = tid & 63, wv = tid >> 6;
  const int wr = wv >> 1, wc = wv & 1;
  const int l15 = lane & 15, g = lane >> 4;
  const int BM = MI * 32;
  const int tm = blockIdx.y, tn = blockIdx.x;
  f32x4 acc[MI][4] = {};
  const int nk = K >> 6;
  const unsigned short* Ag0 = A + (size_t)tm * BM * K;
  const unsigned short* Bg0 = BT + (size_t)tn * 128 * K;
  for (int kt = 0; kt < nk; ++kt) {
#pragma unroll
    for (int it = 0; it < MI; ++it) {
      int chunk = it * 256 + tid;
      int row = chunk >> 3, part = chunk & 7;
      gload16(Ag0 + (size_t)row * K + kt * 64 + part * 8, As + chunk * 8);
    }
#pragma unroll
    for (int it = 0; it < 4; ++it) {
      int chunk = it * 256 + tid;
      int row = chunk >> 3, part = chunk & 7;
      gload16(Bg0 + (size_t)row * K + kt * 64 + part * 8, Bs + chunk * 8);
    }
    __syncthreads();
#pragma unroll
    for (int ks = 0; ks < 2; ++ks) {
      s16x8 af[MI], bf[4];
#pragma unroll
      for (int mi = 0; mi < MI; ++mi)
        af[mi] = *(const s16x8*)(As + (wr * MI * 16 + mi * 16 + l15) * 64 + ks * 32 + g * 8);
#pragma unroll
      for (int ni = 0; ni < 4; ++ni)
        bf[ni] = *(const s16x8*)(Bs + (wc * 64 + ni * 16 + l15) * 64 + ks * 32 + g * 8);
#pragma unroll
      for (int mi = 0; mi < MI; ++mi)
#pragma unroll
        for (int ni = 0; ni < 4; ++ni)
          acc[mi][ni] = __builtin_amdgcn_mfma_f32_16x16x32_bf16(af[mi], bf[ni], acc[mi][ni], 0, 0, 0);
    }
    __syncthreads();
  }
#pragma unroll
  for (int ni = 0; ni < 4; ++ni) {
    int col = tn * 128 + wc * 64 + ni * 16 + l15;
    float bv = bias[col];
#pragma unroll
    for (int mi = 0; mi < MI; ++mi) {
      int row0 = tm * BM + wr * MI * 16 + mi * 16 + g * 4;
#pragma unroll
      for (int r = 0; r < 4; ++r) {
        size_t idx = (size_t)(row0 + r) * N + col;
        float vvv = acc[mi][ni][r] + bv;
        if (MODE == 0) ((unsigned short*)out)[idx] = f2bf(vvv);
        else if (MODE == 1) ((unsigned short*)out)[idx] = f2bf(geluf(vvv));
        else if (MODE == 2) ((float*)out)[idx] = resid[idx] + vvv;
        else ((float*)out)[idx] = vvv;
      }
    }
  }
}

// ---------------- fused causal flash attention v4.1 ----------------
// 512 blocks: 16 q-tile pairs (p, 31-p; 64 q-rows each) x 32 (b,h).
// Block: 4 waves x 16 q-rows. KV tiles of 128. 17 tiles/block (balanced).
// K reg-staged -> LDS stride 40 (conflict-free b128 reads); V^T swizzled.
// log2-domain softmax with defer-max; double-buffered single-barrier pipeline.
__global__ __launch_bounds__(256, 2) void k_attn(const unsigned short* __restrict__ qkv,
                                                 unsigned short* __restrict__ o) {
  __shared__ __align__(16) unsigned short Ks[2][128 * 40];
  __shared__ __align__(16) unsigned short Vs[2][2 * 32 * 72];
  __shared__ __align__(16) unsigned short Ps[4][2 * 16 * 72];
  const int tid = threadIdx.x, lane = tid & 63, w = tid >> 6;
  const int l15 = lane & 15, g = lane >> 4;
  const int p = blockIdx.x;  // 0..15
  const int b = blockIdx.y >> 3, hh = blockIdx.y & 7;
  const size_t base = (size_t)b * TT * 768 + hh * 32;
  const float scl2 = 0.25503492f;  // (1/sqrt(32)) * log2(e)
  const int qt0 = p, qt1 = 31 - p;
  const int nt0 = (qt0 >> 1) + 1;
  const int kr = tid >> 1, khf = tid & 1;     // K stage: 128 rows x 2 halves
  const int vk = tid & 127, vdh = tid >> 7;   // V stage: 128 keys x 2 d-halves
  const int vkh = vk >> 6, vklo = vk & 63;
  unsigned short* Pw = &Ps[w][0];

  s16x8 qf0 = *(const s16x8*)(qkv + base + (size_t)(qt0 * 64 + w * 16 + l15) * 768 + g * 8);
  s16x8 qf1 = *(const s16x8*)(qkv + base + (size_t)(qt1 * 64 + w * 16 + l15) * 768 + g * 8);

  // prologue: stage tile 0 into buf 0
  {
    const unsigned short* kp = qkv + base + (size_t)kr * 768 + 256 + khf * 16;
    s16x8 k0 = *(const s16x8*)kp;
    s16x8 k1 = *(const s16x8*)(kp + 8);
    const unsigned short* vp = qkv + base + (size_t)vk * 768 + 512 + vdh * 16;
    s16x8 v0 = *(const s16x8*)vp;
    s16x8 v1 = *(const s16x8*)(vp + 8);
    *(s16x8*)(Ks[0] + kr * 40 + khf * 16) = k0;
    *(s16x8*)(Ks[0] + kr * 40 + khf * 16 + 8) = k1;
    unsigned short* vb = Vs[0] + vkh * 2304;
#pragma unroll
    for (int e = 0; e < 8; ++e) {
      int d0 = vdh * 16 + e, d1 = vdh * 16 + 8 + e;
      vb[d0 * 72 + (vklo ^ (((d0 >> 3) & 3) << 4))] = (unsigned short)v0[e];
      vb[d1 * 72 + (vklo ^ (((d1 >> 3) & 3) << 4))] = (unsigned short)v1[e];
    }
  }
  __syncthreads();

  f32x4 accO[2] = {};
  float mM = -3.0e38f, ls = 0.f;

  for (int t = 0; t < 17; ++t) {
    const int buf = t & 1;
    const bool ph = (t >= nt0);
    const int qt = ph ? qt1 : qt0;
    const int j = ph ? t - nt0 : t;
    const bool have_next = (t + 1 < 17);
    s16x8 k0n, k1n, v0n, v1n;
    if (have_next) {
      const int jn = (t + 1 >= nt0) ? t + 1 - nt0 : t + 1;
      const unsigned short* kp = qkv + base + (size_t)(jn * 128 + kr) * 768 + 256 + khf * 16;
      k0n = *(const s16x8*)kp;
      k1n = *(const s16x8*)(kp + 8);
      const unsigned short* vp = qkv + base + (size_t)(jn * 128 + vk) * 768 + 512 + vdh * 16;
      v0n = *(const s16x8*)vp;
      v1n = *(const s16x8*)(vp + 8);
    }
    // ---- compute tile (qt, j) from buf ----
    const int rel = qt * 64 + w * 16 - j * 128;   // wave-uniform, >= 0
    const bool full = (rel >= 127);
    int cbm = (rel + 15) >> 4; if (cbm > 7) cbm = 7;
    f32x4 st[8];
#pragma unroll
    for (int cb = 0; cb < 8; ++cb)
      if (cb <= cbm) {
        s16x8 kf = *(const s16x8*)(Ks[buf] + (cb * 16 + l15) * 40 + g * 8);
        f32x4 zz = {};
        st[cb] = __builtin_amdgcn_mfma_f32_16x16x32_bf16(kf, ph ? qf1 : qf0, zz, 0, 0, 0);
      }
    float rmax = -3.0e38f;
#pragma unroll
    for (int cb = 0; cb < 8; ++cb)
      if (cb <= cbm) {
#pragma unroll
        for (int r = 0; r < 4; ++r) {
          float s = st[cb][r] * scl2;
          if (!full && (cb * 16 + g * 4 + r) > rel + l15) s = -3.0e38f;
          st[cb][r] = s;
          rmax = fmaxf(rmax, s);
        }
      }
    rmax = fmaxf(rmax, __shfl_xor(rmax, 16));
    rmax = fmaxf(rmax, __shfl_xor(rmax, 32));
    float al = 1.0f;
    if (!__all(rmax <= mM + 11.5f)) {
      float nm = fmaxf(mM, rmax);
      al = fexp2(mM - nm);
      mM = nm;
#pragma unroll
      for (int r = 0; r < 4; ++r) {
        float aw = __shfl(al, g * 4 + r);
        accO[0][r] *= aw;
        accO[1][r] *= aw;
      }
    }
    float rsum = 0.f;
#pragma unroll
    for (int cb = 0; cb < 8; ++cb)
      if (cb <= cbm) {
        union { unsigned short us[4]; unsigned long long u; } pk;
#pragma unroll
        for (int r = 0; r < 4; ++r) {
          float pe = fexp2(st[cb][r] - mM);
          rsum += pe;
          pk.us[r] = f2bf(pe);
        }
        *(unsigned long long*)(Pw + (cb >> 2) * 1152 + l15 * 72 + (cb & 3) * 16 + g * 4) = pk.u;
      }
    if (cbm < 7 && !(cbm & 1))
      *(unsigned long long*)(Pw + ((cbm + 1) >> 2) * 1152 + l15 * 72 + ((cbm + 1) & 3) * 16 + g * 4) = 0ULL;
    rsum += __shfl_xor(rsum, 16);
    rsum += __shfl_xor(rsum, 32);
    ls = ls * al + rsum;
    asm volatile("s_waitcnt lgkmcnt(0)" ::: "memory");
    __builtin_amdgcn_sched_barrier(0);
    const int kcm = cbm >> 1;
#pragma unroll
    for (int kc = 0; kc < 4; ++kc)
      if (kc <= kcm) {
        s16x8 pa = *(const s16x8*)(Pw + (kc >> 1) * 1152 + l15 * 72 + (kc & 1) * 32 + g * 8);
        s16x8 bv0, bv1;
#pragma unroll
        for (int hb = 0; hb < 2; ++hb) {
          const int d = hb * 16 + l15;
          const int kxr = ((kc & 1) * 32 + g * 8) ^ (((d >> 3) & 3) << 4);
          if (hb == 0) bv0 = *(const s16x8*)(Vs[buf] + (kc >> 1) * 2304 + d * 72 + kxr);
          else bv1 = *(const s16x8*)(Vs[buf] + (kc >> 1) * 2304 + d * 72 + kxr);
        }
        accO[0] = __builtin_amdgcn_mfma_f32_16x16x32_bf16(pa, bv0, accO[0], 0, 0, 0);
        accO[1] = __builtin_amdgcn_mfma_f32_16x16x32_bf16(pa, bv1, accO[1], 0, 0, 0);
      }
    // ---- stage next tile into buf^1, then barrier ----
    if (have_next) {
      *(s16x8*)(Ks[buf ^ 1] + kr * 40 + khf * 16) = k0n;
      *(s16x8*)(Ks[buf ^ 1] + kr * 40 + khf * 16 + 8) = k1n;
      unsigned short* vb = Vs[buf ^ 1] + vkh * 2304;
#pragma unroll
      for (int e = 0; e < 8; ++e) {
        int d0 = vdh * 16 + e, d1 = vdh * 16 + 8 + e;
        vb[d0 * 72 + (vklo ^ (((d0 >> 3) & 3) << 4))] = (unsigned short)v0n[e];
        vb[d1 * 72 + (vklo ^ (((d1 >> 3) & 3) << 4))] = (unsigned short)v1n[e];
      }
      __syncthreads();
    }
    if (t == nt0 - 1) {  // phase 0 done: emit O for qt0, reset state
      float inv = 1.0f / ls;
#pragma unroll
      for (int r = 0; r < 4; ++r) {
        float lv = __shfl(inv, g * 4 + r);
        int row = qt0 * 64 + w * 16 + g * 4 + r;
        o[(size_t)(b * TT + row) * DD + hh * 32 + l15] = f2bf(accO[0][r] * lv);
        o[(size_t)(b * TT + row) * DD + hh * 32 + 16 + l15] = f2bf(accO[1][r] * lv);
      }
      accO[0] = f32x4{};
      accO[1] = f32x4{};
      mM = -3.0e38f;
      ls = 0.f;
    }
  }
  {
    float inv = 1.0f / ls;
#pragma unroll
    for (int r = 0; r < 4; ++r) {
      float lv = __shfl(inv, g * 4 + r);
      int row = qt1 * 64 + w * 16 + g * 4 + r;
      o[(size_t)(b * TT + row) * DD + hh * 32 + l15] = f2bf(accO[0][r] * lv);
      o[(size_t)(b * TT + row) * DD + hh * 32 + 16 + l15] = f2bf(accO[1][r] * lv);
    }
  }
}

extern "C" void kernel_launch(void* const* d_in, const int* in_sizes, int n_in,
                              void* d_out, int out_size, void* d_ws, size_t ws_size,
                              hipStream_t stream) {
  const int* x = (const int*)d_in[0];
  const float* tok = (const float*)d_in[1];
  const float* pos = (const float*)d_in[2];
  const float* ln1w = (const float*)d_in[3];
  const float* ln1b = (const float*)d_in[4];
  const float* qkvw = (const float*)d_in[5];
  const float* qkvb = (const float*)d_in[6];
  const float* outw = (const float*)d_in[7];
  const float* outb = (const float*)d_in[8];
  const float* ln2w = (const float*)d_in[9];
  const float* ln2b = (const float*)d_in[10];
  const float* f1w = (const float*)d_in[11];
  const float* f1b = (const float*)d_in[12];
  const float* f2w = (const float*)d_in[13];
  const float* f2b = (const float*)d_in[14];
  const float* lnfw = (const float*)d_in[15];
  const float* lnfb = (const float*)d_in[16];
  const float* hw = (const float*)d_in[17];
  const float* hb = (const float*)d_in[18];

  char* ws = (char*)d_ws;
  float* h = (float*)(ws + 0);                              //  8 MB
  unsigned short* z = (unsigned short*)(ws + 8388608);      //  4 MB
  unsigned short* qkvB = (unsigned short*)(ws + 12582912);  // 12 MB
  unsigned short* ob = (unsigned short*)(ws + 25165824);    //  4 MB
  unsigned short* a1 = (unsigned short*)(ws + 29360128);    // 16 MB
  unsigned short* wAll = (unsigned short*)(ws + 46137344);  // 18 MB (12 layers) or 1.5 MB (fallback)
  const bool bigws = ws_size >= 65142784ULL;
  unsigned short* wh = (unsigned short*)(ws + (bigws ? 65011712 : 47710208));

  if (bigws)
    k_cast_all<<<dim3(256, 12), dim3(256), 0, stream>>>(qkvw, outw, f1w, f2w, wAll);
  k_cast_tr256<<<dim3(256), dim3(256), 0, stream>>>(hw, wh);
  k_embed<<<dim3(2048), dim3(256), 0, stream>>>(x, tok, pos, h);

  for (int l = 0; l < LL; ++l) {
    unsigned short* wq = wAll + (size_t)(bigws ? l : 0) * 786432;
    unsigned short* wo = wq + 196608;
    unsigned short* w1 = wo + 65536;
    unsigned short* w2 = w1 + 262144;
    if (!bigws)
      k_cast_tr4<<<dim3(1024), dim3(256), 0, stream>>>(
          qkvw + (size_t)l * 196608, outw + (size_t)l * 65536,
          f1w + (size_t)l * 262144, f2w + (size_t)l * 262144, wq, wo, w1, w2);
    k_ln<<<dim3(2048), dim3(256), 0, stream>>>(h, ln1w + l * 256, ln1b + l * 256, z);
    k_gemm<0, 4><<<dim3(6, 64), dim3(256), 0, stream>>>(z, wq, qkvb + l * 768, qkvB, nullptr, 8192, 768, 256);
    k_attn<<<dim3(16, 32), dim3(256), 0, stream>>>(qkvB, ob);
    k_gemm<2, 2><<<dim3(2, 128), dim3(256), 0, stream>>>(ob, wo, outb + l * 256, h, h, 8192, 256, 256);
    k_ln<<<dim3(2048), dim3(256), 0, stream>>>(h, ln2w + l * 256, ln2b + l * 256, z);
    k_gemm<1, 4><<<dim3(8, 64), dim3(256), 0, stream>>>(z, w1, f1b + l * 1024, a1, nullptr, 8192, 1024, 256);
    k_gemm<2, 2><<<dim3(2, 128), dim3(256), 0, stream>>>(a1, w2, f2b + l * 256, h, h, 8192, 256, 1024);
  }

  k_ln<<<dim3(2048), dim3(256), 0, stream>>>(h, lnfw, lnfb, z);
  k_gemm<3, 2><<<dim3(2, 128), dim3(256), 0, stream>>>(z, wh, hb, d_out, nullptr, 8192, 256, 256);
}